// Round 2
// baseline (851.137 us; speedup 1.0000x reference)
//
#include <hip/hip_runtime.h>

typedef __bf16 bf16x8 __attribute__((ext_vector_type(8)));
typedef float f32x4 __attribute__((ext_vector_type(4)));

#define NBLOCKS 2048
#define MBLK 32
#define LDS_STRIDE 196   // f32 elems; %4==0 -> 16B-aligned rows; near-conflict-free b128

__device__ __forceinline__ unsigned short f2bf(float f) {
    unsigned u = __float_as_uint(f);
    u += 0x7fffu + ((u >> 16) & 1u);
    return (unsigned short)(u >> 16);
}

// GT[d*192+c] = bf16(gs*relu(gamma[c][d]) + gb);  biasv[d] = bs*(relu(beta[d])+1e-6) + bb
__global__ void gdn_prep(const float* __restrict__ beta_raw,
                         const float* __restrict__ gamma_raw,
                         const float* __restrict__ beta_scale,
                         const float* __restrict__ beta_bias,
                         const float* __restrict__ gamma_scale,
                         const float* __restrict__ gamma_bias,
                         const int* __restrict__ idxp,
                         unsigned short* __restrict__ GT,
                         float* __restrict__ biasv)
{
    const int idx = idxp[0];
    const float gs = fmaxf(gamma_scale[idx], 0.f);
    const float gb = fmaxf(gamma_bias[idx], 0.f);
    int t = blockIdx.x * blockDim.x + threadIdx.x;  // 0..36863
    if (t < 192 * 192) {
        int c = t / 192;
        int d = t - c * 192;
        float g = fmaxf(gamma_raw[t], 0.f);
        GT[d * 192 + c] = f2bf(gs * g + gb);
    }
    if (t < 192) {
        const float bs = fmaxf(beta_scale[idx], 0.f);
        const float bb = fmaxf(beta_bias[idx], 0.f);
        float b = fmaxf(beta_raw[t], 0.f) + 1e-6f;
        biasv[t] = bs * b + bb;
    }
}

// norm = (x*x) @ G (bf16 MFMA, fp32 acc), out = x * rsqrt(norm + bias)   [all I/O fp32]
// 4 waves/block; wave w owns d-range [48w,48w+48): 18 B-frags in registers.
// Block-iteration = 32 pixels (2 M-tiles of 16 per wave).
__global__ __launch_bounds__(256) void gdn_main(
    const float* __restrict__ x,
    const unsigned short* __restrict__ GT,
    const float* __restrict__ biasv,
    float* __restrict__ out,
    int ntiles)
{
    __shared__ float lrinv[MBLK * LDS_STRIDE];

    const int tid = threadIdx.x;
    const int l   = tid & 63;
    const int w   = tid >> 6;
    const int l15 = l & 15;
    const int lq  = l >> 4;
    const int d0w = w * 48;

    // B frag: B[k=c][n=d], lane: n=l15, k=lq*8+j  -> GT row (d), 16B contiguous
    bf16x8 Bf[3][6];
    {
        const unsigned short* g0 = GT + (d0w + l15) * 192 + lq * 8;
        #pragma unroll
        for (int j = 0; j < 3; ++j)
            #pragma unroll
            for (int kt = 0; kt < 6; ++kt)
                Bf[j][kt] = *(const bf16x8*)(g0 + j * (16 * 192) + kt * 32);
    }
    float biasl[3];
    #pragma unroll
    for (int j = 0; j < 3; ++j) biasl[j] = biasv[d0w + j * 16 + l15];

    for (int tile = blockIdx.x; tile < ntiles; tile += NBLOCKS) {
        const long p0 = (long)tile * MBLK;

        f32x4 acc[2][3];
        #pragma unroll
        for (int m = 0; m < 2; ++m)
            #pragma unroll
            for (int j = 0; j < 3; ++j)
                acc[m][j] = (f32x4){0.f, 0.f, 0.f, 0.f};

        // A frag: A[m=l15][k=lq*8+j]; load 8 fp32, square, round to bf16
        #pragma unroll
        for (int kt = 0; kt < 6; ++kt) {
            #pragma unroll
            for (int m = 0; m < 2; ++m) {
                const float* xp = x + (p0 + m * 16 + l15) * 192 + kt * 32 + lq * 8;
                f32x4 a0 = *(const f32x4*)xp;
                f32x4 a1 = *(const f32x4*)(xp + 4);
                bf16x8 s;
                #pragma unroll
                for (int e = 0; e < 4; ++e) {
                    s[e]     = (__bf16)(a0[e] * a0[e]);
                    s[e + 4] = (__bf16)(a1[e] * a1[e]);
                }
                #pragma unroll
                for (int j = 0; j < 3; ++j)
                    acc[m][j] = __builtin_amdgcn_mfma_f32_16x16x32_bf16(
                        s, Bf[j][kt], acc[m][j], 0, 0, 0);
            }
        }

        __syncthreads();  // previous iteration's LDS readback done
        // C/D layout: col(d)=l15, row(pixel)=lq*4+r
        #pragma unroll
        for (int m = 0; m < 2; ++m)
            #pragma unroll
            for (int j = 0; j < 3; ++j)
                #pragma unroll
                for (int r = 0; r < 4; ++r) {
                    float nv = acc[m][j][r] + biasl[j];
                    lrinv[(m * 16 + lq * 4 + r) * LDS_STRIDE + d0w + j * 16 + l15] =
                        __builtin_amdgcn_rsqf(nv);
                }
        __syncthreads();

        // Epilogue: 32 px * 48 float4-chunks = 1536; 6 per thread, fully coalesced
        #pragma unroll
        for (int i = 0; i < 6; ++i) {
            int q = tid + 256 * i;
            int pp = q / 48;
            int c4 = (q - pp * 48) * 4;
            f32x4 xv = *(const f32x4*)(x + (p0 + pp) * 192 + c4);
            f32x4 rv = *(const f32x4*)&lrinv[pp * LDS_STRIDE + c4];
            f32x4 ov;
            #pragma unroll
            for (int h = 0; h < 4; ++h) ov[h] = xv[h] * rv[h];
            *(f32x4*)(out + (p0 + pp) * 192 + c4) = ov;
        }
    }
}

extern "C" void kernel_launch(void* const* d_in, const int* in_sizes, int n_in,
                              void* d_out, int out_size, void* d_ws, size_t ws_size,
                              hipStream_t stream)
{
    const float* x           = (const float*)d_in[0];
    const float* beta_raw    = (const float*)d_in[1];
    const float* gamma_raw   = (const float*)d_in[2];
    const float* beta_scale  = (const float*)d_in[3];
    const float* beta_bias   = (const float*)d_in[4];
    const float* gamma_scale = (const float*)d_in[5];
    const float* gamma_bias  = (const float*)d_in[6];
    const int*   idxp        = (const int*)d_in[7];
    float*       out         = (float*)d_out;

    unsigned short* GT    = (unsigned short*)d_ws;
    float*          biasv = (float*)((char*)d_ws + 192 * 192 * sizeof(unsigned short));

    gdn_prep<<<144, 256, 0, stream>>>(beta_raw, gamma_raw, beta_scale, beta_bias,
                                      gamma_scale, gamma_bias, idxp, GT, biasv);

    const int P = out_size / 192;       // 524288 pixels
    const int ntiles = P / MBLK;        // 16384
    gdn_main<<<NBLOCKS, 256, 0, stream>>>(x, GT, biasv, out, ntiles);
}